// Round 1
// baseline (822.167 us; speedup 1.0000x reference)
//
#include <hip/hip_runtime.h>

#define N_TOK 8192
#define DIM   1024
#define HID   2048
#define NEXP  8
#define TOPK  2
#define BM 128
#define BN 128
#define BK 64
#define MAXROWS (N_TOK*TOPK + NEXP*BM)   /* 17408 */
#define MAXTILES (MAXROWS/BM)            /* 136 */

typedef float f32x4 __attribute__((ext_vector_type(4)));
typedef short bf16x8 __attribute__((ext_vector_type(8)));

static __device__ __forceinline__ unsigned short f2bf(float f){
    union { float f; unsigned u; } v; v.f = f;
    unsigned r = v.u + 0x7FFFu + ((v.u >> 16) & 1u);
    return (unsigned short)(r >> 16);
}

static __device__ __forceinline__ void gload_lds16(const void* g, void* l){
    __builtin_amdgcn_global_load_lds((const __attribute__((address_space(1))) void*)g,
                                     (__attribute__((address_space(3))) void*)l,
                                     16, 0, 0);
}

// ---------------- weight convert + transpose: src [z][R][C] f32 -> dst [z][C][R] bf16
__global__ __launch_bounds__(256) void cvt_transpose_moe(
    const float* __restrict__ src, unsigned short* __restrict__ dst, int R, int C)
{
    __shared__ float tile[32][33];
    const size_t plane = (size_t)R * C;
    const float* s = src + (size_t)blockIdx.z * plane;
    unsigned short* d = dst + (size_t)blockIdx.z * plane;
    int c0 = blockIdx.x * 32, r0 = blockIdx.y * 32;
    int tx = threadIdx.x & 31, ty = threadIdx.x >> 5;
    #pragma unroll
    for (int i = 0; i < 4; ++i)
        tile[ty + i*8][tx] = s[(size_t)(r0 + ty + i*8) * C + c0 + tx];
    __syncthreads();
    #pragma unroll
    for (int i = 0; i < 4; ++i)
        d[(size_t)(c0 + ty + i*8) * R + r0 + tx] = f2bf(tile[tx][ty + i*8]);
}

// ---------------- router: 1 wave per token
__global__ __launch_bounds__(256) void router_moe(
    const float* __restrict__ x, const float* __restrict__ Wg, const float* __restrict__ bg,
    float* __restrict__ gate_probs, float* __restrict__ gate_mask,
    int* __restrict__ tk_e, float* __restrict__ tk_w, int* __restrict__ counts)
{
    const int lane = threadIdx.x & 63;
    const int n = blockIdx.x * 4 + (threadIdx.x >> 6);
    const float* xr = x + (size_t)n * DIM;

    float acc[NEXP];
    #pragma unroll
    for (int e = 0; e < NEXP; ++e) acc[e] = 0.f;
    #pragma unroll 4
    for (int i = 0; i < DIM/64; ++i) {
        int d = i*64 + lane;
        float xv = xr[d];
        const float4* wrow = (const float4*)(Wg + (size_t)d * NEXP);
        float4 w0 = wrow[0], w1 = wrow[1];
        acc[0] += xv*w0.x; acc[1] += xv*w0.y; acc[2] += xv*w0.z; acc[3] += xv*w0.w;
        acc[4] += xv*w1.x; acc[5] += xv*w1.y; acc[6] += xv*w1.z; acc[7] += xv*w1.w;
    }
    #pragma unroll
    for (int off = 32; off > 0; off >>= 1) {
        #pragma unroll
        for (int e = 0; e < NEXP; ++e) acc[e] += __shfl_xor(acc[e], off, 64);
    }
    float lgt[NEXP];
    float mx = acc[0] + bg[0];
    #pragma unroll
    for (int e = 0; e < NEXP; ++e) { lgt[e] = acc[e] + bg[e]; mx = fmaxf(mx, lgt[e]); }
    float s = 0.f;
    #pragma unroll
    for (int e = 0; e < NEXP; ++e) { lgt[e] = expf(lgt[e] - mx); s += lgt[e]; }
    float inv = 1.f / s;
    #pragma unroll
    for (int e = 0; e < NEXP; ++e) lgt[e] *= inv;   // probs

    int i1 = 0;
    #pragma unroll
    for (int e = 1; e < NEXP; ++e) if (lgt[e] > lgt[i1]) i1 = e;
    int i2 = (i1 == 0) ? 1 : 0;
    #pragma unroll
    for (int e = 0; e < NEXP; ++e) if (e != i1 && lgt[e] > lgt[i2]) i2 = e;
    float wsum = lgt[i1] + lgt[i2] + 1e-8f;
    float w1n = lgt[i1] / wsum, w2n = lgt[i2] / wsum;

    if (lane < NEXP) {
        gate_probs[(size_t)n*NEXP + lane] = lgt[lane];
        gate_mask [(size_t)n*NEXP + lane] = (lane == i1) ? w1n : (lane == i2) ? w2n : 0.f;
    }
    if (lane == 0) {
        tk_e[n*TOPK]   = i1; tk_e[n*TOPK+1] = i2;
        tk_w[n*TOPK]   = w1n; tk_w[n*TOPK+1] = w2n;
        atomicAdd(&counts[i1], 1);
        atomicAdd(&counts[i2], 1);
    }
}

// ---------------- scan: bases, cursors, tile schedule (single thread; E=8 trivial)
__global__ void scan_moe(const int* __restrict__ counts, int* __restrict__ bases,
                         int* __restrict__ cursors, int* __restrict__ sched_e,
                         int* __restrict__ sched_row, int* __restrict__ total_tiles)
{
    if (threadIdx.x != 0 || blockIdx.x != 0) return;
    int base = 0, t = 0;
    for (int e = 0; e < NEXP; ++e) {
        bases[e] = base; cursors[e] = 0;
        int nt = (counts[e] + BM - 1) / BM;
        for (int i = 0; i < nt; ++i) { sched_e[t] = e; sched_row[t] = base + i*BM; ++t; }
        base += nt * BM;
    }
    *total_tiles = t;
}

// ---------------- gather: token rows -> expert-grouped bf16 rows
__global__ __launch_bounds__(256) void gather_moe(
    const float* __restrict__ x, const int* __restrict__ tk_e, const float* __restrict__ tk_w,
    const int* __restrict__ bases, int* __restrict__ cursors,
    unsigned short* __restrict__ Xg, int* __restrict__ pair_token, float* __restrict__ pair_w)
{
    __shared__ int rows_s[TOPK];
    const int n = blockIdx.x;
    if (threadIdx.x < TOPK) {
        int e = tk_e[n*TOPK + threadIdx.x];
        int slot = atomicAdd(&cursors[e], 1);
        int r = bases[e] + slot;
        rows_s[threadIdx.x] = r;
        pair_token[r] = n;
        pair_w[r] = tk_w[n*TOPK + threadIdx.x];
    }
    __syncthreads();
    float4 xv = ((const float4*)(x + (size_t)n * DIM))[threadIdx.x];
    ushort4 b;
    b.x = f2bf(xv.x); b.y = f2bf(xv.y); b.z = f2bf(xv.z); b.w = f2bf(xv.w);
    #pragma unroll
    for (int kk = 0; kk < TOPK; ++kk)
        ((ushort4*)(Xg + (size_t)rows_s[kk] * DIM))[threadIdx.x] = b;
}

// ---------------- grouped GEMM, m97 structure: 128x128 tile, BK=64, 4 waves, swizzled LDS
// MODE 0: h = relu(Xg @ W1t^T + b1) -> bf16 Hout
// MODE 1: out[tok] += w * (Hb @ W2t^T + b2)  (atomic f32)
template<int MODE>
__global__ __launch_bounds__(256) void gemm_moe(
    const unsigned short* __restrict__ A,    // [rows][K] bf16
    const unsigned short* __restrict__ Bt,   // [E][HID][K] bf16 (transposed weights)
    const float* __restrict__ bias,          // [E][HID]
    const int* __restrict__ sched_e, const int* __restrict__ sched_row,
    const int* __restrict__ total_tiles,
    unsigned short* __restrict__ Hout,
    const int* __restrict__ pair_token, const float* __restrict__ pair_w,
    float* __restrict__ out)
{
    if ((int)blockIdx.x >= *total_tiles) return;
    constexpr int K = (MODE == 0) ? DIM : HID;
    const int e    = sched_e[blockIdx.x];
    const int row0 = sched_row[blockIdx.x];
    const int col0 = blockIdx.y * BN;
    const unsigned short* Be = Bt + (size_t)e * HID * K;

    __shared__ unsigned short Alds[BM * BK];   // 16 KB, rows of 128B, XOR-swizzled 16B slots
    __shared__ unsigned short Blds[BN * BK];   // 16 KB

    const int tid  = threadIdx.x;
    const int wv   = tid >> 6, lane = tid & 63;
    const int wr   = wv >> 1,  wc   = wv & 1;
    const int lrow = lane & 15, lg  = lane >> 4;
    const int sr   = lane >> 3, si  = lane & 7;
    const int gc16 = si ^ sr;                  // pre-swizzled global 16B-slot index

    f32x4 acc[4][4] = {};

    const unsigned short* Ab = A  + (size_t)row0 * K + gc16 * 8;
    const unsigned short* Bb = Be + (size_t)col0 * K + gc16 * 8;

    for (int k0 = 0; k0 < K; k0 += BK) {
        __syncthreads();
        #pragma unroll
        for (int j = 0; j < 4; ++j) {
            int chunk = wv*4 + j;              // 8 rows per 1KB chunk
            gload_lds16(Ab + (size_t)(chunk*8 + sr) * K + k0, (char*)Alds + chunk*1024);
        }
        #pragma unroll
        for (int j = 0; j < 4; ++j) {
            int chunk = wv*4 + j;
            gload_lds16(Bb + (size_t)(chunk*8 + sr) * K + k0, (char*)Blds + chunk*1024);
        }
        __syncthreads();
        #pragma unroll
        for (int kk = 0; kk < BK; kk += 32) {
            bf16x8 af[4], bfr[4];
            #pragma unroll
            for (int mb = 0; mb < 4; ++mb) {
                int r = wr*64 + mb*16 + lrow;
                int c16 = ((kk >> 3) + lg) ^ (r & 7);
                af[mb] = *(const bf16x8*)((const char*)Alds + r*128 + c16*16);
            }
            #pragma unroll
            for (int nb = 0; nb < 4; ++nb) {
                int r = wc*64 + nb*16 + lrow;
                int c16 = ((kk >> 3) + lg) ^ (r & 7);
                bfr[nb] = *(const bf16x8*)((const char*)Blds + r*128 + c16*16);
            }
            #pragma unroll
            for (int mb = 0; mb < 4; ++mb)
                #pragma unroll
                for (int nb = 0; nb < 4; ++nb)
                    acc[mb][nb] = __builtin_amdgcn_mfma_f32_16x16x32_bf16(
                                      af[mb], bfr[nb], acc[mb][nb], 0, 0, 0);
        }
    }

    // epilogue: C/D layout col=lane&15, row=(lane>>4)*4+reg  [verified m89/m91]
    if constexpr (MODE == 0) {
        #pragma unroll
        for (int nb = 0; nb < 4; ++nb) {
            int col = col0 + wc*64 + nb*16 + lrow;
            float bv = bias[(size_t)e*HID + col];
            #pragma unroll
            for (int mb = 0; mb < 4; ++mb) {
                int rb = row0 + wr*64 + mb*16 + lg*4;
                #pragma unroll
                for (int j = 0; j < 4; ++j) {
                    float v = fmaxf(acc[mb][nb][j] + bv, 0.f);
                    Hout[(size_t)(rb + j) * HID + col] = f2bf(v);
                }
            }
        }
    } else {
        float bv[4]; int cols[4];
        #pragma unroll
        for (int nb = 0; nb < 4; ++nb) {
            cols[nb] = col0 + wc*64 + nb*16 + lrow;
            bv[nb] = bias[(size_t)e*HID + cols[nb]];
        }
        #pragma unroll
        for (int mb = 0; mb < 4; ++mb) {
            #pragma unroll
            for (int j = 0; j < 4; ++j) {
                int r = row0 + wr*64 + mb*16 + lg*4 + j;
                int tok = pair_token[r];
                if (tok < 0) continue;         // pad row
                float w = pair_w[r];
                float* orow = out + (size_t)tok * HID;
                #pragma unroll
                for (int nb = 0; nb < 4; ++nb)
                    atomicAdd(orow + cols[nb], w * (acc[mb][nb][j] + bv[nb]));
            }
        }
    }
}

extern "C" void kernel_launch(void* const* d_in, const int* in_sizes, int n_in,
                              void* d_out, int out_size, void* d_ws, size_t ws_size,
                              hipStream_t stream)
{
    const float* x  = (const float*)d_in[0];
    const float* Wg = (const float*)d_in[1];
    const float* bg = (const float*)d_in[2];
    const float* W1 = (const float*)d_in[3];
    const float* b1 = (const float*)d_in[4];
    const float* W2 = (const float*)d_in[5];
    const float* b2 = (const float*)d_in[6];

    float* out        = (float*)d_out;                       // [N, HID]
    float* gate_probs = out + (size_t)N_TOK * HID;           // [N, E]
    float* gate_mask  = gate_probs + (size_t)N_TOK * NEXP;   // [N, E]

    // workspace carve (~198 MiB total)
    char* p = (char*)d_ws;
    auto carve = [&](size_t bytes) { char* r = p; p += (bytes + 255) & ~(size_t)255; return r; };
    unsigned short* W1t = (unsigned short*)carve((size_t)NEXP*DIM*HID*2);  // [e][h][d]
    unsigned short* W2t = (unsigned short*)carve((size_t)NEXP*HID*HID*2);  // [e][j][h]
    unsigned short* Xg  = (unsigned short*)carve((size_t)MAXROWS*DIM*2);
    unsigned short* Hb  = (unsigned short*)carve((size_t)MAXROWS*HID*2);
    int*   pair_token = (int*)  carve((size_t)MAXROWS*4);
    float* pair_w     = (float*)carve((size_t)MAXROWS*4);
    int*   tk_e       = (int*)  carve((size_t)N_TOK*TOPK*4);
    float* tk_w       = (float*)carve((size_t)N_TOK*TOPK*4);
    int*   counts     = (int*)  carve(256);
    int*   bases      = (int*)  carve(256);
    int*   cursors    = (int*)  carve(256);
    int*   sched_e    = (int*)  carve(1024);
    int*   sched_row  = (int*)  carve(1024);
    int*   total_tiles= (int*)  carve(256);

    hipMemsetAsync(out, 0, (size_t)N_TOK*HID*4, stream);
    hipMemsetAsync(counts, 0, 256, stream);
    hipMemsetAsync(pair_token, 0xFF, (size_t)MAXROWS*4, stream);  // -1 = pad

    cvt_transpose_moe<<<dim3(HID/32, DIM/32, NEXP), 256, 0, stream>>>(W1, W1t, DIM, HID);
    cvt_transpose_moe<<<dim3(HID/32, HID/32, NEXP), 256, 0, stream>>>(W2, W2t, HID, HID);
    router_moe<<<N_TOK/4, 256, 0, stream>>>(x, Wg, bg, gate_probs, gate_mask, tk_e, tk_w, counts);
    scan_moe<<<1, 64, 0, stream>>>(counts, bases, cursors, sched_e, sched_row, total_tiles);
    gather_moe<<<N_TOK, 256, 0, stream>>>(x, tk_e, tk_w, bases, cursors, Xg, pair_token, pair_w);
    gemm_moe<0><<<dim3(MAXTILES, HID/BN), 256, 0, stream>>>(
        Xg, W1t, b1, sched_e, sched_row, total_tiles, Hb, nullptr, nullptr, nullptr);
    gemm_moe<1><<<dim3(MAXTILES, HID/BN), 256, 0, stream>>>(
        Hb, W2t, b2, sched_e, sched_row, total_tiles, nullptr, pair_token, pair_w, out);
}

// Round 2
// 669.540 us; speedup vs baseline: 1.2280x; 1.2280x over previous
//
#include <hip/hip_runtime.h>

#define N_TOK 8192
#define DIM   1024
#define HID   2048
#define NEXP  8
#define TOPK  2
#define BM 256
#define BN 256
#define BK 64
#define NTHREADS 512
#define MAXROWS (N_TOK*TOPK + NEXP*BM)   /* 18432 */
#define MAXRT   (MAXROWS/BM)             /* 72 row tiles */
#define NT_COL  (HID/BN)                 /* 8 col tiles */

typedef float f32x4 __attribute__((ext_vector_type(4)));
typedef short bf16x8 __attribute__((ext_vector_type(8)));

static __device__ __forceinline__ unsigned short f2bf(float f){
    union { float f; unsigned u; } v; v.f = f;
    unsigned r = v.u + 0x7FFFu + ((v.u >> 16) & 1u);
    return (unsigned short)(r >> 16);
}
static __device__ __forceinline__ float bf2f(unsigned short u){
    union { unsigned u; float f; } v; v.u = ((unsigned)u) << 16;
    return v.f;
}

static __device__ __forceinline__ void gload_lds16(const void* g, void* l){
    __builtin_amdgcn_global_load_lds((const __attribute__((address_space(1))) void*)g,
                                     (__attribute__((address_space(3))) void*)l,
                                     16, 0, 0);
}

// ---------------- weight convert + transpose: src [z][R][C] f32 -> dst [z][C][R] bf16
__global__ __launch_bounds__(256) void cvt_transpose_moe(
    const float* __restrict__ src, unsigned short* __restrict__ dst, int R, int C)
{
    __shared__ float tile[32][33];
    const size_t plane = (size_t)R * C;
    const float* s = src + (size_t)blockIdx.z * plane;
    unsigned short* d = dst + (size_t)blockIdx.z * plane;
    int c0 = blockIdx.x * 32, r0 = blockIdx.y * 32;
    int tx = threadIdx.x & 31, ty = threadIdx.x >> 5;
    #pragma unroll
    for (int i = 0; i < 4; ++i)
        tile[ty + i*8][tx] = s[(size_t)(r0 + ty + i*8) * C + c0 + tx];
    __syncthreads();
    #pragma unroll
    for (int i = 0; i < 4; ++i)
        d[(size_t)(c0 + ty + i*8) * R + r0 + tx] = f2bf(tile[tx][ty + i*8]);
}

// ---------------- router: 1 wave per token
__global__ __launch_bounds__(256) void router_moe(
    const float* __restrict__ x, const float* __restrict__ Wg, const float* __restrict__ bg,
    float* __restrict__ gate_probs, float* __restrict__ gate_mask,
    int* __restrict__ tk_e, float* __restrict__ tk_w, int* __restrict__ counts)
{
    const int lane = threadIdx.x & 63;
    const int n = blockIdx.x * 4 + (threadIdx.x >> 6);
    const float* xr = x + (size_t)n * DIM;

    float acc[NEXP];
    #pragma unroll
    for (int e = 0; e < NEXP; ++e) acc[e] = 0.f;
    #pragma unroll 4
    for (int i = 0; i < DIM/64; ++i) {
        int d = i*64 + lane;
        float xv = xr[d];
        const float4* wrow = (const float4*)(Wg + (size_t)d * NEXP);
        float4 w0 = wrow[0], w1 = wrow[1];
        acc[0] += xv*w0.x; acc[1] += xv*w0.y; acc[2] += xv*w0.z; acc[3] += xv*w0.w;
        acc[4] += xv*w1.x; acc[5] += xv*w1.y; acc[6] += xv*w1.z; acc[7] += xv*w1.w;
    }
    #pragma unroll
    for (int off = 32; off > 0; off >>= 1) {
        #pragma unroll
        for (int e = 0; e < NEXP; ++e) acc[e] += __shfl_xor(acc[e], off, 64);
    }
    float lgt[NEXP];
    float mx = acc[0] + bg[0];
    #pragma unroll
    for (int e = 0; e < NEXP; ++e) { lgt[e] = acc[e] + bg[e]; mx = fmaxf(mx, lgt[e]); }
    float s = 0.f;
    #pragma unroll
    for (int e = 0; e < NEXP; ++e) { lgt[e] = expf(lgt[e] - mx); s += lgt[e]; }
    float inv = 1.f / s;
    #pragma unroll
    for (int e = 0; e < NEXP; ++e) lgt[e] *= inv;   // probs

    int i1 = 0;
    #pragma unroll
    for (int e = 1; e < NEXP; ++e) if (lgt[e] > lgt[i1]) i1 = e;
    int i2 = (i1 == 0) ? 1 : 0;
    #pragma unroll
    for (int e = 0; e < NEXP; ++e) if (e != i1 && lgt[e] > lgt[i2]) i2 = e;
    float wsum = lgt[i1] + lgt[i2] + 1e-8f;
    float w1n = lgt[i1] / wsum, w2n = lgt[i2] / wsum;

    if (lane < NEXP) {
        gate_probs[(size_t)n*NEXP + lane] = lgt[lane];
        gate_mask [(size_t)n*NEXP + lane] = (lane == i1) ? w1n : (lane == i2) ? w2n : 0.f;
    }
    if (lane == 0) {
        tk_e[n*TOPK]   = i1; tk_e[n*TOPK+1] = i2;
        tk_w[n*TOPK]   = w1n; tk_w[n*TOPK+1] = w2n;
        atomicAdd(&counts[i1], 1);
        atomicAdd(&counts[i2], 1);
    }
}

// ---------------- scan: bases, cursors, tile schedule
__global__ void scan_moe(const int* __restrict__ counts, int* __restrict__ bases,
                         int* __restrict__ cursors, int* __restrict__ sched_e,
                         int* __restrict__ sched_row, int* __restrict__ total_tiles)
{
    if (threadIdx.x != 0 || blockIdx.x != 0) return;
    int base = 0, t = 0;
    for (int e = 0; e < NEXP; ++e) {
        bases[e] = base; cursors[e] = 0;
        int nt = (counts[e] + BM - 1) / BM;
        for (int i = 0; i < nt; ++i) { sched_e[t] = e; sched_row[t] = base + i*BM; ++t; }
        base += nt * BM;
    }
    *total_tiles = t;
}

// ---------------- gather: token rows -> expert-grouped bf16 rows
// pair_token[r] = n*2 + slot  (-1 for pad rows)
__global__ __launch_bounds__(256) void gather_moe(
    const float* __restrict__ x, const int* __restrict__ tk_e,
    const int* __restrict__ bases, int* __restrict__ cursors,
    unsigned short* __restrict__ Xg, int* __restrict__ pair_token)
{
    __shared__ int rows_s[TOPK];
    const int n = blockIdx.x;
    if (threadIdx.x < TOPK) {
        int e = tk_e[n*TOPK + threadIdx.x];
        int slot = atomicAdd(&cursors[e], 1);
        int r = bases[e] + slot;
        rows_s[threadIdx.x] = r;
        pair_token[r] = n*2 + threadIdx.x;
    }
    __syncthreads();
    float4 xv = ((const float4*)(x + (size_t)n * DIM))[threadIdx.x];
    ushort4 b;
    b.x = f2bf(xv.x); b.y = f2bf(xv.y); b.z = f2bf(xv.z); b.w = f2bf(xv.w);
    #pragma unroll
    for (int kk = 0; kk < TOPK; ++kk)
        ((ushort4*)(Xg + (size_t)rows_s[kk] * DIM))[threadIdx.x] = b;
}

// ---------------- grouped GEMM: 256x256 tile, BK=64, 8 waves, depth-2 counted-vmcnt pipeline
// MODE 0: Out = relu(A @ Bt^T + bias) -> bf16, linear rows (Hb)
// MODE 1: P[pair] = A @ Bt^T + bias   -> bf16, token-slot scatter (no atomics)
template<int K, int MODE>
__global__ __launch_bounds__(512, 2) void gemm_moe(
    const unsigned short* __restrict__ A,    // [rows][K] bf16
    const unsigned short* __restrict__ Bt,   // [E][HID][K] bf16
    const float* __restrict__ bias,          // [E][HID]
    const int* __restrict__ sched_e, const int* __restrict__ sched_row,
    const int* __restrict__ total_tiles,
    unsigned short* __restrict__ Out,
    const int* __restrict__ pair_token)
{
    // T1: bijective XCD swizzle over the full linear grid (576 = 72*8, %8==0)
    const int nwg  = gridDim.x * gridDim.y;
    const int orig = blockIdx.y * gridDim.x + blockIdx.x;
    const int q = nwg >> 3, r8 = nwg & 7, xcd = orig & 7, lin = orig >> 3;
    const int wg = (xcd < r8 ? xcd*(q+1) : r8*(q+1) + (xcd-r8)*q) + lin;
    const int rt = wg / NT_COL, ct = wg % NT_COL;
    if (rt >= *total_tiles) return;

    const int e    = sched_e[rt];
    const int row0 = sched_row[rt];
    const int col0 = ct * BN;
    const unsigned short* Be = Bt + (size_t)e * HID * K;

    __shared__ __align__(1024) char lds[131072];   // 2 bufs x (A 32KB + B 32KB)

    const int tid  = threadIdx.x;
    const int wv   = tid >> 6, lane = tid & 63;
    const int wr   = wv >> 2,  wc   = wv & 3;      // 2 x 4 wave grid
    const int lrow = lane & 15, lg  = lane >> 4;
    const int sr   = lane >> 3, si  = lane & 7;
    const int gc16 = si ^ sr;                      // pre-swizzled global 16B-slot (T2)

    const unsigned short* Ab = A  + (size_t)row0 * K + gc16 * 8;
    const unsigned short* Bb = Be + (size_t)col0 * K + gc16 * 8;

    f32x4 acc[8][4] = {};

    auto STAGE = [&](int buf, int k0) {
        char* Ad = lds + buf*65536;
        char* Bd = Ad + 32768;
        #pragma unroll
        for (int j = 0; j < 4; ++j) {
            int chunk = wv*4 + j;                  // 8 rows / chunk, 32 chunks
            gload_lds16(Ab + (size_t)(chunk*8 + sr) * K + k0, Ad + chunk*1024);
        }
        #pragma unroll
        for (int j = 0; j < 4; ++j) {
            int chunk = wv*4 + j;
            gload_lds16(Bb + (size_t)(chunk*8 + sr) * K + k0, Bd + chunk*1024);
        }
    };

    auto COMPUTE = [&](int buf) {
        const char* Al = lds + buf*65536;
        const char* Bl = Al + 32768;
        #pragma unroll
        for (int kk = 0; kk < 2; ++kk) {
            bf16x8 bfr[4];
            #pragma unroll
            for (int nb = 0; nb < 4; ++nb) {
                int r = wc*64 + nb*16 + lrow;
                int c16 = (kk*4 + lg) ^ (r & 7);
                bfr[nb] = *(const bf16x8*)(Bl + r*128 + c16*16);
            }
            #pragma unroll
            for (int h = 0; h < 2; ++h) {
                bf16x8 af[4];
                #pragma unroll
                for (int m = 0; m < 4; ++m) {
                    int r = wr*128 + h*64 + m*16 + lrow;
                    int c16 = (kk*4 + lg) ^ (r & 7);
                    af[m] = *(const bf16x8*)(Al + r*128 + c16*16);
                }
                __builtin_amdgcn_s_setprio(1);
                #pragma unroll
                for (int m = 0; m < 4; ++m)
                    #pragma unroll
                    for (int nb = 0; nb < 4; ++nb)
                        acc[h*4+m][nb] = __builtin_amdgcn_mfma_f32_16x16x32_bf16(
                                             af[m], bfr[nb], acc[h*4+m][nb], 0, 0, 0);
                __builtin_amdgcn_s_setprio(0);
            }
        }
    };

    constexpr int NT = K / BK;
    STAGE(0, 0);
    int cur = 0;
    for (int t = 0; t < NT - 1; ++t) {
        STAGE(cur ^ 1, (t + 1) * BK);             // prefetch next tile (stays in flight)
        asm volatile("s_waitcnt vmcnt(8)" ::: "memory");  // only current tile's loads drained
        __builtin_amdgcn_sched_barrier(0);
        __builtin_amdgcn_s_barrier();
        __builtin_amdgcn_sched_barrier(0);
        COMPUTE(cur);
        __builtin_amdgcn_sched_barrier(0);
        __builtin_amdgcn_s_barrier();
        __builtin_amdgcn_sched_barrier(0);
        cur ^= 1;
    }
    asm volatile("s_waitcnt vmcnt(0)" ::: "memory");
    __builtin_amdgcn_sched_barrier(0);
    __builtin_amdgcn_s_barrier();
    __builtin_amdgcn_sched_barrier(0);
    COMPUTE(cur);

    // epilogue: C/D layout col=lane&15, row=(lane>>4)*4+reg
    if constexpr (MODE == 0) {
        #pragma unroll
        for (int nb = 0; nb < 4; ++nb) {
            int col = col0 + wc*64 + nb*16 + lrow;
            float bv = bias[(size_t)e*HID + col];
            #pragma unroll
            for (int mb = 0; mb < 8; ++mb) {
                int rb = row0 + wr*128 + mb*16 + lg*4;
                #pragma unroll
                for (int j = 0; j < 4; ++j) {
                    float v = fmaxf(acc[mb][nb][j] + bv, 0.f);
                    Out[(size_t)(rb + j) * HID + col] = f2bf(v);
                }
            }
        }
    } else {
        float bv[4]; int cols[4];
        #pragma unroll
        for (int nb = 0; nb < 4; ++nb) {
            cols[nb] = col0 + wc*64 + nb*16 + lrow;
            bv[nb] = bias[(size_t)e*HID + cols[nb]];
        }
        #pragma unroll
        for (int mb = 0; mb < 8; ++mb) {
            #pragma unroll
            for (int j = 0; j < 4; ++j) {
                int r = row0 + wr*128 + mb*16 + lg*4 + j;
                int pair = pair_token[r];
                if (pair < 0) continue;            // pad row
                size_t prow = (size_t)(pair & 1) * N_TOK + (pair >> 1);
                #pragma unroll
                for (int nb = 0; nb < 4; ++nb)
                    Out[prow * HID + cols[nb]] = f2bf(acc[mb][nb][j] + bv[nb]);
            }
        }
    }
}

// ---------------- combine: out[n] = w0*P[0][n] + w1*P[1][n]
__global__ __launch_bounds__(256) void combine_moe(
    const unsigned short* __restrict__ P, const float* __restrict__ tk_w,
    float* __restrict__ out)
{
    const int n = blockIdx.x;
    const float w0 = tk_w[n*2], w1 = tk_w[n*2+1];
    const int c = threadIdx.x * 8;
    bf16x8 a = *(const bf16x8*)(P + (size_t)n * HID + c);
    bf16x8 b = *(const bf16x8*)(P + (size_t)(N_TOK + n) * HID + c);
    float4 o0, o1;
    float* op = &o0.x;
    #pragma unroll
    for (int i = 0; i < 4; ++i)
        op[i] = w0 * bf2f((unsigned short)a[i]) + w1 * bf2f((unsigned short)b[i]);
    float* op1 = &o1.x;
    #pragma unroll
    for (int i = 0; i < 4; ++i)
        op1[i] = w0 * bf2f((unsigned short)a[4+i]) + w1 * bf2f((unsigned short)b[4+i]);
    float4* dst = (float4*)(out + (size_t)n * HID + c);
    dst[0] = o0; dst[1] = o1;
}

extern "C" void kernel_launch(void* const* d_in, const int* in_sizes, int n_in,
                              void* d_out, int out_size, void* d_ws, size_t ws_size,
                              hipStream_t stream)
{
    const float* x  = (const float*)d_in[0];
    const float* Wg = (const float*)d_in[1];
    const float* bg = (const float*)d_in[2];
    const float* W1 = (const float*)d_in[3];
    const float* b1 = (const float*)d_in[4];
    const float* W2 = (const float*)d_in[5];
    const float* b2 = (const float*)d_in[6];

    float* out        = (float*)d_out;                       // [N, HID]
    float* gate_probs = out + (size_t)N_TOK * HID;           // [N, E]
    float* gate_mask  = gate_probs + (size_t)N_TOK * NEXP;   // [N, E]

    // workspace carve (~205 MiB); P aliases dead W1t+Xg after GEMM1
    char* p = (char*)d_ws;
    auto carve = [&](size_t bytes) { char* r = p; p += (bytes + 255) & ~(size_t)255; return r; };
    unsigned short* W2t = (unsigned short*)carve((size_t)NEXP*HID*HID*2);  // 64 MB [e][j][h]
    unsigned short* Hb  = (unsigned short*)carve((size_t)MAXROWS*HID*2);   // 72 MB
    unsigned short* W1t = (unsigned short*)carve((size_t)NEXP*DIM*HID*2);  // 32 MB [e][h][d]
    unsigned short* Xg  = (unsigned short*)carve((size_t)MAXROWS*DIM*2);   // 36 MB
    unsigned short* P   = W1t;   // 64 MB alias over W1t(32)+Xg(36); both dead at GEMM2
    int*   pair_token = (int*)  carve((size_t)MAXROWS*4);
    int*   tk_e       = (int*)  carve((size_t)N_TOK*TOPK*4);
    float* tk_w       = (float*)carve((size_t)N_TOK*TOPK*4);
    int*   counts     = (int*)  carve(256);
    int*   bases      = (int*)  carve(256);
    int*   cursors    = (int*)  carve(256);
    int*   sched_e    = (int*)  carve(1024);
    int*   sched_row  = (int*)  carve(1024);
    int*   total_tiles= (int*)  carve(256);

    hipMemsetAsync(counts, 0, 256, stream);
    hipMemsetAsync(pair_token, 0xFF, (size_t)MAXROWS*4, stream);  // -1 = pad

    cvt_transpose_moe<<<dim3(HID/32, DIM/32, NEXP), 256, 0, stream>>>(W1, W1t, DIM, HID);
    cvt_transpose_moe<<<dim3(HID/32, HID/32, NEXP), 256, 0, stream>>>(W2, W2t, HID, HID);
    router_moe<<<N_TOK/4, 256, 0, stream>>>(x, Wg, bg, gate_probs, gate_mask, tk_e, tk_w, counts);
    scan_moe<<<1, 64, 0, stream>>>(counts, bases, cursors, sched_e, sched_row, total_tiles);
    gather_moe<<<N_TOK, 256, 0, stream>>>(x, tk_e, bases, cursors, Xg, pair_token);
    gemm_moe<DIM, 0><<<dim3(MAXRT, NT_COL), NTHREADS, 0, stream>>>(
        Xg, W1t, b1, sched_e, sched_row, total_tiles, Hb, nullptr);
    gemm_moe<HID, 1><<<dim3(MAXRT, NT_COL), NTHREADS, 0, stream>>>(
        Hb, W2t, b2, sched_e, sched_row, total_tiles, P, pair_token);
    combine_moe<<<N_TOK, 256, 0, stream>>>(P, tk_w, out);
}